// Round 1
// baseline (275.213 us; speedup 1.0000x reference)
//
#include <hip/hip_runtime.h>
#include <math.h>

#define NTOT 10790
#define EPSF 1e-6f

__device__ __forceinline__ float block_reduce_sum(float v, float* red) {
    int tid = threadIdx.x;
    red[tid] = v; __syncthreads();
    for (int off = 128; off > 0; off >>= 1) {
        if (tid < off) red[tid] += red[tid + off];
        __syncthreads();
    }
    float r = red[0];
    __syncthreads();
    return r;
}

// grid (3 levels, 8 batch), block 256
__global__ __launch_bounds__(256) void mask_kernel(const int* __restrict__ mask,
                                                   float* __restrict__ wsm0,
                                                   float* __restrict__ wsm1,
                                                   float* __restrict__ wsm2,
                                                   float* __restrict__ msum) {
    int level = blockIdx.x, b = blockIdx.y, tid = threadIdx.x;
    int h = 64 >> level, w = h, S = 8 << level, HW = h * w;
    float* wsm = (level == 0) ? wsm0 : ((level == 1) ? wsm1 : wsm2);
    const int* mb = mask + (size_t)b * 512 * 512;
    float acc = 0.f;
    for (int n = tid; n < HW; n += 256) {
        int y = n / w, x = n - y * w;
        float mv = (float)mb[y * S * 512 + x * S];
        wsm[b * HW + n] = mv;
        acc += mv;
    }
    __shared__ float red[256];
    float s = block_reduce_sum(acc, red);
    if (tid == 0) msum[b * 3 + level] = s;
}

// grid (256 channels, 8 batch), block 256 over pixels
__global__ __launch_bounds__(256) void sreduce_kernel(const float* __restrict__ s,
                                                      const float* __restrict__ wsm,
                                                      float* __restrict__ fgnum,
                                                      float* __restrict__ tot,
                                                      int level, int HW) {
    int c = blockIdx.x, b = blockIdx.y, tid = threadIdx.x;
    const float* sb = s + ((size_t)(b * 256) + c) * HW;
    const float* mb = wsm + b * HW;
    float af = 0.f, at = 0.f;
    for (int n = tid; n < HW; n += 256) {
        float x = sb[n];
        float m = mb[n];
        at += x;
        af = fmaf(x, m, af);
    }
    __shared__ float redA[256], redB[256];
    redA[tid] = af; redB[tid] = at; __syncthreads();
    for (int off = 128; off > 0; off >>= 1) {
        if (tid < off) { redA[tid] += redA[tid + off]; redB[tid] += redB[tid + off]; }
        __syncthreads();
    }
    if (tid == 0) {
        int base = (level * 8 + b) * 256 + c;
        fgnum[base] = redA[0];
        tot[base]   = redB[0];
    }
}

// grid 8 (batch), block 256 (channels)
__global__ __launch_bounds__(256) void protos_kernel(const float* __restrict__ R,
                                                     const float* __restrict__ fgnum,
                                                     const float* __restrict__ tot,
                                                     const float* __restrict__ msum,
                                                     float* __restrict__ c0v,
                                                     float* __restrict__ c1v,
                                                     float* __restrict__ rn0v,
                                                     float* __restrict__ rn1v,
                                                     float* __restrict__ minv,
                                                     int level, int HW) {
    int b = blockIdx.x, c = threadIdx.x;
    __shared__ float red[256];
    int base = (level * 8 + b) * 256;
    float ms = msum[b * 3 + level];
    float denf = ms + EPSF;
    float denb = ((float)HW - ms) + EPSF;
    float fg = fgnum[base + c];
    float tt = tot[base + c];
    float pf = fg / denf;            // proto_fg
    float pb = (tt - fg) / denb;     // proto_bg
    float nf = block_reduce_sum(pf * pf, red);
    float nb = block_reduce_sum(pb * pb, red);
    float C1 = pf / (sqrtf(nf) + EPSF);   // row 1 = fg
    float C0 = pb / (sqrtf(nb) + EPSF);   // row 0 = bg
    c0v[base + c] = C0;
    c1v[base + c] = C1;
    float r0 = R[c], r1 = R[256 + c];
    float n0 = block_reduce_sum(r0 * r0, red);
    float n1 = block_reduce_sum(r1 * r1, red);
    float R0 = r0 / (sqrtf(n0) + EPSF);
    float R1 = r1 / (sqrtf(n1) + EPSF);
    rn0v[base + c] = R0;
    rn1v[base + c] = R1;
    float a  = block_reduce_sum(C0 * C0, red);
    float bb = block_reduce_sum(C0 * C1, red);
    float cc = block_reduce_sum(C1 * C1, red);
    if (c == 0) {
        float det = a * cc - bb * bb;
        float id = 1.0f / det;
        float* M = minv + (level * 8 + b) * 4;
        M[0] = cc * id; M[1] = -bb * id; M[2] = -bb * id; M[3] = a * id;
    }
}

// grid (HW/64, 8 batch), block 256 = 64 pixels x 4 channel-groups
__global__ __launch_bounds__(256) void transform_kernel(const float* __restrict__ x,
                                                        float* __restrict__ out,
                                                        const float* __restrict__ c0v,
                                                        const float* __restrict__ c1v,
                                                        const float* __restrict__ rn0v,
                                                        const float* __restrict__ rn1v,
                                                        const float* __restrict__ minv,
                                                        const float* __restrict__ wsm,
                                                        float* __restrict__ vout,
                                                        float* __restrict__ partials,
                                                        int level, int HW, int col_off, int is_s) {
    int b = blockIdx.y;
    int n0 = blockIdx.x * 64;
    int tid = threadIdx.x;
    int p = tid & 63, g = tid >> 6;
    __shared__ float sc0[256], sc1[256], srn0[256], srn1[256];
    __shared__ float st0[4][64], st1[4][64];
    __shared__ float su0[64], su1[64];
    int base = (level * 8 + b) * 256;
    sc0[tid] = c0v[base + tid];
    sc1[tid] = c1v[base + tid];
    srn0[tid] = rn0v[base + tid];
    srn1[tid] = rn1v[base + tid];
    __syncthreads();

    const float* xb = x + (size_t)(b * 256) * HW;
    int n = n0 + p;
    float t0 = 0.f, t1 = 0.f;
    #pragma unroll 8
    for (int i = 0; i < 64; i++) {
        int c = g * 64 + i;
        float xv = xb[(size_t)c * HW + n];
        t0 = fmaf(sc0[c], xv, t0);
        t1 = fmaf(sc1[c], xv, t1);
    }
    st0[g][p] = t0; st1[g][p] = t1;
    __syncthreads();

    if (tid < 64) {
        float a0 = st0[0][p] + st0[1][p] + st0[2][p] + st0[3][p];
        float a1 = st1[0][p] + st1[1][p] + st1[2][p] + st1[3][p];
        const float* M = minv + (level * 8 + b) * 4;
        float u0 = M[0] * a0 + M[1] * a1;
        float u1 = M[1] * a0 + M[3] * a1;
        su0[p] = u0; su1[p] = u1;
        if (vout) {
            vout[((size_t)b * 4096 + n) * 2 + 0] = u0;
            vout[((size_t)b * 4096 + n) * 2 + 1] = u1;
        }
        if (is_s) {
            float m = wsm[b * HW + n];
            float s0 = m * u0, s1 = m * u1, s2 = u0, s3 = u1;
            for (int off = 32; off > 0; off >>= 1) {
                s0 += __shfl_down(s0, off, 64);
                s1 += __shfl_down(s1, off, 64);
                s2 += __shfl_down(s2, off, 64);
                s3 += __shfl_down(s3, off, 64);
            }
            if (p == 0) {
                float* pp = partials + (((level * 8 + b) * 64) + blockIdx.x) * 4;
                pp[0] = s0; pp[1] = s1; pp[2] = s2; pp[3] = s3;
            }
        }
    }
    __syncthreads();

    float* ob = out + (size_t)(b * 256) * NTOT + col_off + n0;
    #pragma unroll 8
    for (int i = 0; i < 64; i++) {
        int c = g * 64 + i;
        ob[(size_t)c * NTOT + p] = fmaf(srn0[c], su0[p], srn1[c] * su1[p]);
    }
}

// grid (8 batch, 3 level), block 256
__global__ __launch_bounds__(256) void protoT_kernel(float* __restrict__ out,
                                                     const float* __restrict__ partials,
                                                     const float* __restrict__ rn0v,
                                                     const float* __restrict__ rn1v,
                                                     const float* __restrict__ msum) {
    int b = blockIdx.x, level = blockIdx.y, tid = threadIdx.x;
    const int HWs[3] = {4096, 1024, 256};
    const int nblks[3] = {64, 16, 4};
    __shared__ float A[4];
    if (tid == 0) {
        float s0 = 0, s1 = 0, s2 = 0, s3 = 0;
        const float* pp = partials + ((size_t)(level * 8 + b) * 64) * 4;
        int nb = nblks[level];
        for (int i = 0; i < nb; i++) {
            s0 += pp[i * 4 + 0]; s1 += pp[i * 4 + 1];
            s2 += pp[i * 4 + 2]; s3 += pp[i * 4 + 3];
        }
        float ms = msum[b * 3 + level];
        float denf = ms + EPSF;
        float denb = ((float)HWs[level] - ms) + EPSF;
        A[0] = s0 / denf;          // fg avg of u0
        A[1] = s1 / denf;          // fg avg of u1
        A[2] = (s2 - s0) / denb;   // bg avg of u0
        A[3] = (s3 - s1) / denb;   // bg avg of u1
    }
    __syncthreads();
    int base = (level * 8 + b) * 256;
    float r0 = rn0v[base + tid], r1 = rn1v[base + tid];
    size_t row = ((size_t)(b * 256) + tid) * NTOT;
    out[row + 10752 + level] = fmaf(r0, A[0], r1 * A[1]);
    out[row + 10755 + level] = fmaf(r0, A[2], r1 * A[3]);
}

// grid 8 (batch), block 256
__global__ __launch_bounds__(256) void topk_kernel(float* __restrict__ out,
                                                   const float* __restrict__ v,
                                                   const float* __restrict__ wsm0,
                                                   const float* __restrict__ msum,
                                                   const float* __restrict__ rn0v,
                                                   const float* __restrict__ rn1v) {
    int b = blockIdx.x, tid = threadIdx.x;
    __shared__ float sc[4096];
    __shared__ float sr0[256], sr1[256];
    __shared__ unsigned int taken[128];
    __shared__ float rv[256];
    __shared__ int ri[256];
    __shared__ int bidx[32];
    sr0[tid] = rn0v[b * 256 + tid];   // level 0
    sr1[tid] = rn1v[b * 256 + tid];
    if (tid < 128) taken[tid] = 0u;
    __syncthreads();

    bool validmask = msum[b * 3 + 0] > 0.0f;
    for (int n = tid; n < 4096; n += 256) {
        float v0 = v[((size_t)b * 4096 + n) * 2 + 0];
        float v1 = v[((size_t)b * 4096 + n) * 2 + 1];
        float ss = 0.f;
        #pragma unroll 8
        for (int c = 0; c < 256; c++) {
            float e = fmaf(sr0[c], v0, sr1[c] * v1);
            ss = fmaf(e, e, ss);
        }
        float score = sqrtf(ss);
        float m = validmask ? wsm0[b * 4096 + n] : 1.0f;
        sc[n] = (m >= 0.5f) ? score : -INFINITY;
    }
    __syncthreads();

    for (int j = 0; j < 32; j++) {
        float bv = -INFINITY;
        int bi = 1 << 30;
        for (int n = tid; n < 4096; n += 256) {
            if (taken[n >> 5] & (1u << (n & 31))) continue;
            float s = sc[n];
            if (s > bv || (s == bv && n < bi)) { bv = s; bi = n; }
        }
        rv[tid] = bv; ri[tid] = bi;
        __syncthreads();
        for (int off = 128; off > 0; off >>= 1) {
            if (tid < off) {
                if (rv[tid + off] > rv[tid] ||
                    (rv[tid + off] == rv[tid] && ri[tid + off] < ri[tid])) {
                    rv[tid] = rv[tid + off];
                    ri[tid] = ri[tid + off];
                }
            }
            __syncthreads();
        }
        if (tid == 0) {
            bidx[j] = ri[0];
            taken[ri[0] >> 5] |= 1u << (ri[0] & 31);
        }
        __syncthreads();
    }

    // tokens: out[b, c, 10758+j] = Rn0[c]*v0[idx] + Rn1[c]*v1[idx]
    size_t row = ((size_t)(b * 256) + tid) * NTOT;
    for (int j = 0; j < 32; j++) {
        int idx = bidx[j];
        float v0 = v[((size_t)b * 4096 + idx) * 2 + 0];
        float v1 = v[((size_t)b * 4096 + idx) * 2 + 1];
        out[row + 10758 + j] = fmaf(sr0[tid], v0, sr1[tid] * v1);
    }
}

extern "C" void kernel_launch(void* const* d_in, const int* in_sizes, int n_in,
                              void* d_out, int out_size, void* d_ws, size_t ws_size,
                              hipStream_t stream) {
    // dict order: q1,s1,r1, q2,s2,r2, q3,s3,r3, support_mask, k
    const float* q[3] = {(const float*)d_in[0], (const float*)d_in[3], (const float*)d_in[6]};
    const float* s[3] = {(const float*)d_in[1], (const float*)d_in[4], (const float*)d_in[7]};
    const float* r[3] = {(const float*)d_in[2], (const float*)d_in[5], (const float*)d_in[8]};
    const int* mask = (const int*)d_in[9];
    float* out = (float*)d_out;
    float* W = (float*)d_ws;

    float* wsm0 = W;              // 8*4096      = 32768
    float* wsm1 = W + 32768;      // 8*1024      =  8192
    float* wsm2 = W + 40960;      // 8*256       =  2048
    float* msum = W + 43008;      // 8*3 (pad)   ->   32
    float* fgnum = W + 43040;     // 3*8*256     =  6144
    float* tot  = W + 49184;      // 6144
    float* c0v  = W + 55328;      // 6144
    float* c1v  = W + 61472;      // 6144
    float* rn0v = W + 67616;      // 6144
    float* rn1v = W + 73760;      // 6144
    float* minv = W + 79904;      // 3*8*4 = 96
    float* vbuf = W + 80000;      // 8*4096*2 = 65536
    float* part = W + 145536;     // 3*8*64*4 = 6144  (end 151680 floats ~ 593 KB)

    const int HWs[3] = {4096, 1024, 256};
    float* wsm[3] = {wsm0, wsm1, wsm2};
    const int qoff[3] = {0, 4096, 5120};
    const int soff[3] = {5376, 9472, 10496};

    mask_kernel<<<dim3(3, 8), 256, 0, stream>>>(mask, wsm0, wsm1, wsm2, msum);

    for (int l = 0; l < 3; l++)
        sreduce_kernel<<<dim3(256, 8), 256, 0, stream>>>(s[l], wsm[l], fgnum, tot, l, HWs[l]);

    for (int l = 0; l < 3; l++)
        protos_kernel<<<8, 256, 0, stream>>>(r[l], fgnum, tot, msum,
                                             c0v, c1v, rn0v, rn1v, minv, l, HWs[l]);

    for (int l = 0; l < 3; l++) {
        transform_kernel<<<dim3(HWs[l] / 64, 8), 256, 0, stream>>>(
            q[l], out, c0v, c1v, rn0v, rn1v, minv,
            nullptr, nullptr, nullptr, l, HWs[l], qoff[l], 0);
        transform_kernel<<<dim3(HWs[l] / 64, 8), 256, 0, stream>>>(
            s[l], out, c0v, c1v, rn0v, rn1v, minv,
            wsm[l], (l == 0) ? vbuf : nullptr, part, l, HWs[l], soff[l], 1);
    }

    protoT_kernel<<<dim3(8, 3), 256, 0, stream>>>(out, part, rn0v, rn1v, msum);

    topk_kernel<<<8, 256, 0, stream>>>(out, vbuf, wsm0, msum, rn0v, rn1v);
}